// Round 3
// baseline (416.324 us; speedup 1.0000x reference)
//
#include <hip/hip_runtime.h>

// SpikeLoss: loss = 0.5 * sum((outputs - psp(target))^2)
// psp: syn_t = syn_{t-1}*0.8 + x_t, emit syn_t/5   (tau=5)
// Shape [B=16, C=128, H=16, W=16, T=100], T contiguous. 524288 neurons.
//
// R3: coalesced wave-parallel scan, float4/lane, 25 lanes per neuron,
// TWO neurons per wave (half-wave each) sharing the shuffle instructions.
// In-lane prefix (3 fma) + 4-step cross-lane Kogge-Stone (d=16 step dropped:
// coeff a^64 ~ 6e-7, negligible vs absmax threshold). Register prefetch of
// the next neuron-pair keeps VMEM in flight across the shuffle chain.

#define T4 25                            // float4 slots per neuron (T=100)
#define N_NEURONS (16 * 128 * 16 * 16)   // 524288
#define BLOCK 256
#define GRID_P 2048                      // 8192 waves
#define NPW 64                           // neurons per wave
#define ITERS (NPW / 2)                  // 32 iterations, 2 neurons each

__device__ __forceinline__ float wave_acc(const float4* __restrict__ t4,
                                          const float4* __restrict__ o4,
                                          int wave, int lane) {
  const int sub = lane & 31;      // position within half-wave
  const int half = lane >> 5;     // 0: neuron A, 1: neuron B
  const bool active = sub < T4;
  const int n0 = wave * NPW + half;

  const float4 z = make_float4(0.f, 0.f, 0.f, 0.f);
  float acc = 0.0f;

  int idx = n0 * T4 + sub;
  float4 x = active ? t4[idx] : z;
  float4 o = active ? o4[idx] : z;

  for (int i = 0; i < ITERS; ++i) {
    float4 xn = z, on = z;
    if (i + 1 < ITERS) {
      int idn = (n0 + 2 * (i + 1)) * T4 + sub;
      if (active) { xn = t4[idn]; on = o4[idn]; }
    }

    // in-lane prefix over 4 timesteps: X = syn contribution ending at t=4*sub+3
    float X = fmaf(fmaf(fmaf(x.x, 0.8f, x.y), 0.8f, x.z), 0.8f, x.w);

    // cross-lane inclusive scan over 25 sub-lanes; coeff = a^(4d), a=0.8.
    // Half-wave isolation: lane 32+s reads lane 32+s-d (same neuron) and the
    // sub>=d predicate kills any cross-half read.
    float y;
    y = __shfl_up(X, 1);  if (sub >= 1) X = fmaf(y, 0.4096f, X);
    y = __shfl_up(X, 2);  if (sub >= 2) X = fmaf(y, 0.16777216f, X);
    y = __shfl_up(X, 4);  if (sub >= 4) X = fmaf(y, 2.81474977e-2f, X);
    y = __shfl_up(X, 8);  if (sub >= 8) X = fmaf(y, 7.92281625e-4f, X);
    // (d=16 step dropped: a^64 ~ 6.28e-7 attenuation)

    // reconstruct syn at the 4 in-lane timesteps (1/0.8 = 1.25 exact)
    float s3 = X;
    float s2 = (s3 - x.w) * 1.25f;
    float s1 = (s2 - x.z) * 1.25f;
    float s0 = (s1 - x.y) * 1.25f;

    float d0 = fmaf(s0, -0.2f, o.x);
    float d1 = fmaf(s1, -0.2f, o.y);
    float d2 = fmaf(s2, -0.2f, o.z);
    float d3 = fmaf(s3, -0.2f, o.w);
    if (active)
      acc = fmaf(d0, d0, fmaf(d1, d1, fmaf(d2, d2, fmaf(d3, d3, acc))));

    x = xn; o = on;
  }
  return acc;
}

__device__ __forceinline__ void block_reduce_store(float acc, float* dst,
                                                   float scale) {
#pragma unroll
  for (int off = 32; off > 0; off >>= 1) acc += __shfl_down(acc, off, 64);
  __shared__ float wsum[BLOCK / 64];
  const int lane = threadIdx.x & 63;
  const int wid = threadIdx.x >> 6;
  if (lane == 0) wsum[wid] = acc;
  __syncthreads();
  if (threadIdx.x == 0)
    dst[0] = scale * (wsum[0] + wsum[1] + wsum[2] + wsum[3]);
}

__global__ __launch_bounds__(BLOCK) void spike_loss_partial(
    const float* __restrict__ outputs,
    const float* __restrict__ target,
    float* __restrict__ partial) {
  const int lane = threadIdx.x & 63;
  const int wave = (blockIdx.x * BLOCK + threadIdx.x) >> 6;
  float acc = wave_acc(reinterpret_cast<const float4*>(target),
                       reinterpret_cast<const float4*>(outputs), wave, lane);
  block_reduce_store(acc, partial + blockIdx.x, 1.0f);
}

// Deterministic final reduction over per-block partials; applies the 0.5.
__global__ __launch_bounds__(256) void spike_loss_final(
    const float* __restrict__ partial, float* __restrict__ out, int nparts) {
  float acc = 0.0f;
  for (int i = threadIdx.x; i < nparts; i += 256) acc += partial[i];
#pragma unroll
  for (int off = 32; off > 0; off >>= 1) acc += __shfl_down(acc, off, 64);
  __shared__ float wsum[4];
  const int lane = threadIdx.x & 63;
  const int wid = threadIdx.x >> 6;
  if (lane == 0) wsum[wid] = acc;
  __syncthreads();
  if (threadIdx.x == 0) out[0] = 0.5f * (wsum[0] + wsum[1] + wsum[2] + wsum[3]);
}

// Fallback if d_ws is unusably small: atomic finish into d_out.
__global__ __launch_bounds__(BLOCK) void spike_loss_atomic(
    const float* __restrict__ outputs,
    const float* __restrict__ target,
    float* __restrict__ out) {
  const int lane = threadIdx.x & 63;
  const int wave = (blockIdx.x * BLOCK + threadIdx.x) >> 6;
  float acc = wave_acc(reinterpret_cast<const float4*>(target),
                       reinterpret_cast<const float4*>(outputs), wave, lane);
#pragma unroll
  for (int off = 32; off > 0; off >>= 1) acc += __shfl_down(acc, off, 64);
  __shared__ float wsum[BLOCK / 64];
  const int wid = threadIdx.x >> 6;
  if (lane == 0) wsum[wid] = acc;
  __syncthreads();
  if (threadIdx.x == 0)
    atomicAdd(out, 0.5f * (wsum[0] + wsum[1] + wsum[2] + wsum[3]));
}

extern "C" void kernel_launch(void* const* d_in, const int* in_sizes, int n_in,
                              void* d_out, int out_size, void* d_ws, size_t ws_size,
                              hipStream_t stream) {
  const float* outputs = (const float*)d_in[0];
  const float* target = (const float*)d_in[1];
  float* out = (float*)d_out;

  if (ws_size >= GRID_P * sizeof(float)) {
    float* partial = (float*)d_ws;
    spike_loss_partial<<<GRID_P, BLOCK, 0, stream>>>(outputs, target, partial);
    spike_loss_final<<<1, 256, 0, stream>>>(partial, out, GRID_P);
  } else {
    hipMemsetAsync(out, 0, sizeof(float), stream);
    spike_loss_atomic<<<GRID_P, BLOCK, 0, stream>>>(outputs, target, out);
  }
}